// Round 6
// baseline (1077.926 us; speedup 1.0000x reference)
//
#include <hip/hip_runtime.h>
#include <stdint.h>
#include <math.h>

// Problem constants: B=2, H=16, S=2048, D=64
#define BB 2
#define HH 16
#define SS 2048
#define DD 64
#define QE  ((size_t)BB * HH * SS * DD)  // elements per tensor
#define PME ((size_t)BB * SS * SS)       // packed-mask elements (uint16)

typedef __attribute__((ext_vector_type(8))) short short8;   // bf16x8 MFMA frag
typedef __attribute__((ext_vector_type(4))) float float4v;  // fp32x4 accum

__device__ __forceinline__ float bflo(unsigned int u){ return __uint_as_float(u << 16); }
__device__ __forceinline__ float bfhi(unsigned int u){ return __uint_as_float(u & 0xffff0000u); }
__device__ __forceinline__ unsigned short f2bf(float f){
  unsigned int u = __float_as_uint(f);
  u += 0x7fffu + ((u >> 16) & 1u);   // RNE
  return (unsigned short)(u >> 16);
}
__device__ __forceinline__ unsigned int pk2(float lo, float hi){
  return ((unsigned int)f2bf(hi) << 16) | (unsigned int)f2bf(lo);
}

// ---------------------------------------------------------------------------
// Mask dtype detection (verified rounds 0-5).
// ---------------------------------------------------------------------------
__global__ void detect_mask_mode(const unsigned int* __restrict__ mw, int* __restrict__ mode_out){
  __shared__ int a32, af, a64;
  const int t = threadIdx.x;
  if (t == 0){ a32 = 1; af = 1; a64 = 1; }
  __syncthreads();
  int ok32 = 1, okf = 1, ok64 = 1;
  for (int idx = t; idx < 4096; idx += 256){
    const unsigned int w = mw[idx];
    if (w > 1u) ok32 = 0;
    if (w != 0u && w != 0x3F800000u) okf = 0;
    if ((idx & 1) ? (w != 0u) : (w > 1u)) ok64 = 0;
  }
  if (!ok32) atomicAnd(&a32, 0);
  if (!okf)  atomicAnd(&af, 0);
  if (!ok64) atomicAnd(&a64, 0);
  __syncthreads();
  if (t == 0){
    int mode;
    if (a64)      mode = 3;
    else if (a32) mode = 0;
    else if (af)  mode = 2;
    else          mode = 1;
    *mode_out = mode;
  }
}

// ---------------------------------------------------------------------------
// Pack mask[b][h][q][k] -> pm[b][q][k] uint16 (bit h set if masked).
// (verified round 3)
// ---------------------------------------------------------------------------
__global__ __launch_bounds__(256) void pack_mask_kernel(
    const void* __restrict__ mask, const int* __restrict__ modep,
    unsigned short* __restrict__ pm)
{
  const int mode = *modep;
  const size_t tid  = (size_t)blockIdx.x * 256 + threadIdx.x;
  const size_t base = tid * 8;
  const size_t bq   = base >> 11;
  const int    k0   = (int)(base & (SS - 1));
  const size_t b    = bq >> 11;
  const size_t q    = bq & (SS - 1);

  unsigned short outv[8] = {0,0,0,0,0,0,0,0};

  if (mode == 0 || mode == 2){
    const unsigned int* p = (const unsigned int*)mask;
    #pragma unroll
    for (int h = 0; h < HH; ++h){
      const size_t e = ((b * HH + h) * SS + q) * SS + k0;
      const uint4 a = *(const uint4*)(p + e);
      const uint4 c = *(const uint4*)(p + e + 4);
      const unsigned short bit = (unsigned short)(1u << h);
      if (a.x) outv[0] |= bit;  if (a.y) outv[1] |= bit;
      if (a.z) outv[2] |= bit;  if (a.w) outv[3] |= bit;
      if (c.x) outv[4] |= bit;  if (c.y) outv[5] |= bit;
      if (c.z) outv[6] |= bit;  if (c.w) outv[7] |= bit;
    }
  } else if (mode == 1){
    const unsigned char* p = (const unsigned char*)mask;
    #pragma unroll
    for (int h = 0; h < HH; ++h){
      const size_t e = ((b * HH + h) * SS + q) * SS + k0;
      uint2 a = *(const uint2*)(p + e);
      const unsigned short bit = (unsigned short)(1u << h);
      #pragma unroll
      for (int j = 0; j < 4; ++j){
        if ((a.x >> (8*j)) & 0xffu) outv[j]     |= bit;
        if ((a.y >> (8*j)) & 0xffu) outv[4 + j] |= bit;
      }
    }
  } else {
    const unsigned int* p = (const unsigned int*)mask;
    #pragma unroll
    for (int h = 0; h < HH; ++h){
      const size_t e = (((b * HH + h) * SS + q) * SS + k0) * 2;
      const unsigned short bit = (unsigned short)(1u << h);
      #pragma unroll
      for (int j = 0; j < 4; ++j){
        const uint4 a = *(const uint4*)(p + e + j * 4);
        if (a.x) outv[j * 2]     |= bit;
        if (a.z) outv[j * 2 + 1] |= bit;
      }
    }
  }

  uint4 w;
  w.x = (unsigned int)outv[0] | ((unsigned int)outv[1] << 16);
  w.y = (unsigned int)outv[2] | ((unsigned int)outv[3] << 16);
  w.z = (unsigned int)outv[4] | ((unsigned int)outv[5] << 16);
  w.w = (unsigned int)outv[6] | ((unsigned int)outv[7] << 16);
  *(uint4*)(pm + base) = w;
}

// ---------------------------------------------------------------------------
// Prep: fp32 -> bf16 (scale folded for Q)
// ---------------------------------------------------------------------------
__global__ void conv_bf16_kernel(const float* __restrict__ src, unsigned short* __restrict__ dst, float scale){
  const size_t i = ((size_t)blockIdx.x * 256 + threadIdx.x) * 8;
  const float4 a = *(const float4*)(src + i);
  const float4 b = *(const float4*)(src + i + 4);
  uint4 o;
  o.x = pk2(a.x * scale, a.y * scale);
  o.y = pk2(a.z * scale, a.w * scale);
  o.z = pk2(b.x * scale, b.y * scale);
  o.w = pk2(b.z * scale, b.w * scale);
  *(uint4*)(dst + i) = o;
}

// ---------------------------------------------------------------------------
// Prep: V[b,h,k,d] fp32 -> Vt[b,h,d,k] bf16 (verified round 1)
// ---------------------------------------------------------------------------
__global__ void transp_v_kernel(const float* __restrict__ V, unsigned short* __restrict__ Vt){
  __shared__ unsigned short tile[64][66];
  const int t  = threadIdx.x;
  const int kt = blockIdx.x & 31;
  const int bh = blockIdx.x >> 5;
  {
    const int kr = t >> 2, dc = (t & 3) * 16;
    const float* src = V + ((size_t)bh * SS + (size_t)(kt * 64 + kr)) * DD + dc;
    #pragma unroll
    for (int c = 0; c < 4; ++c){
      const float4 v = *(const float4*)(src + c * 4);
      tile[kr][dc + c * 4 + 0] = f2bf(v.x);
      tile[kr][dc + c * 4 + 1] = f2bf(v.y);
      tile[kr][dc + c * 4 + 2] = f2bf(v.z);
      tile[kr][dc + c * 4 + 3] = f2bf(v.w);
    }
  }
  __syncthreads();
  {
    const int dr = t >> 2, kc = (t & 3) * 16;
    unsigned short* dst = Vt + ((size_t)bh * DD + dr) * SS + kt * 64 + kc;
    unsigned int w[8];
    #pragma unroll
    for (int p = 0; p < 8; ++p){
      w[p] = (unsigned int)tile[kc + 2*p][dr] | ((unsigned int)tile[kc + 2*p + 1][dr] << 16);
    }
    uint4 o0 = { w[0], w[1], w[2], w[3] };
    uint4 o1 = { w[4], w[5], w[6], w[7] };
    *(uint4*)(dst)     = o0;
    *(uint4*)(dst + 8) = o1;
  }
}

// ---------------------------------------------------------------------------
// Main fused kernel — single-barrier k-loop with double-buffered W:
//  * W[2] ping-pong (2x32 KB = 64 KB LDS): write W[ks&1] -> barrier ->
//    PV reads W[ks&1] while the NEXT step's Q/K loads issue behind it.
//    (>1-barrier run-ahead impossible: a wave must pass barrier ks+1 before
//    touching W[ks&1] again, and laggards haven't passed barrier ks.)
//  * Q A-frags from global each step (32 KB tile, L1/L2-hot) — no Qf LDS.
//  * Score phase: 4 chunks x 4 heads, 16 loads batched ahead of 8 MFMAs.
//  * Packed-mask words for step ks+1 prefetched right after ks's consume.
//  * NO min-waves launch bound: LDS caps at 2 blocks/CU anyway; capping VGPR
//    at 128 caused scratch spills in rounds 4-5 (PV pipeline ~160 live regs).
//  * XCD swizzle (verified round 5): blocks sharing (b,kc) -> same XCD.
// Grid: 512 blocks x 256 thr. split-k=2, atomic epilogue (verified cheap).
// ---------------------------------------------------------------------------
__global__ __launch_bounds__(256) void attn_main_kernel(
    const unsigned short* __restrict__ Qb, const unsigned short* __restrict__ Kb,
    const unsigned short* __restrict__ Vt, const unsigned short* __restrict__ pm,
    float* __restrict__ out)
{
  __shared__ unsigned short W[2][HH * 16 * 64];   // 2 x 32768 B

  const int t = threadIdx.x;
  const int wave = t >> 6, lane = t & 63, quad = lane >> 4, l16 = lane & 15;

  const int L  = blockIdx.x;
  const int b  = (L >> 1) & 1;
  const int kc = (L >> 2) & 1;
  const int q0 = (((L >> 3) << 1) | (L & 1)) * 16;

  float4v O[4][4];   // [head-within-wave][d-tile]
  #pragma unroll
  for (int i = 0; i < 4; ++i)
    #pragma unroll
    for (int j = 0; j < 4; ++j) O[i][j] = (float4v){0.f, 0.f, 0.f, 0.f};

  const unsigned short* qbase = Qb + ((size_t)(b * HH) * SS + (size_t)(q0 + l16)) * DD + quad * 8;
  const unsigned short* kbas0 = Kb + ((size_t)(b * HH) * SS + (size_t)(kc * 1024 + wave * 16 + l16)) * DD + quad * 8;
  const unsigned short* pmrow = pm + ((size_t)b * SS + (size_t)(q0 + quad * 4)) * SS + (size_t)(kc * 1024 + wave * 16 + l16);

  // mask prefetch for ks=0
  unsigned int m16[4];
  #pragma unroll
  for (int r = 0; r < 4; ++r) m16[r] = (unsigned int)pmrow[(size_t)r * SS];

  #pragma unroll 1
  for (int ks = 0; ks < 16; ++ks){
    const int k0 = (kc * 16 + ks) * 64;

    // ---- scores: 4 chunks of 4 heads; Q+K loads batched ahead of MFMAs ----
    unsigned int sp[HH][2];
    const unsigned short* kbase = kbas0 + (size_t)ks * 64 * DD;

    #pragma unroll
    for (int ch = 0; ch < 4; ++ch){
      short8 qa0[4], qa1[4], kb0[4], kb1[4];
      #pragma unroll
      for (int j = 0; j < 4; ++j){
        const int h = ch * 4 + j;
        const unsigned short* qp = qbase + (size_t)h * (SS * DD);
        const unsigned short* kp = kbase + (size_t)h * (SS * DD);
        qa0[j] = *(const short8*)(qp);
        qa1[j] = *(const short8*)(qp + 32);
        kb0[j] = *(const short8*)(kp);
        kb1[j] = *(const short8*)(kp + 32);
      }
      #pragma unroll
      for (int j = 0; j < 4; ++j){
        const int h = ch * 4 + j;
        float4v c = (float4v){0.f, 0.f, 0.f, 0.f};
        c = __builtin_amdgcn_mfma_f32_16x16x32_bf16(qa0[j], kb0[j], c, 0, 0, 0);
        c = __builtin_amdgcn_mfma_f32_16x16x32_bf16(qa1[j], kb1[j], c, 0, 0, 0);
        #pragma unroll
        for (int r = 0; r < 4; ++r) if ((m16[r] >> h) & 1u) c[r] = -INFINITY;
        sp[h][0] = pk2(c[0], c[1]);
        sp[h][1] = pk2(c[2], c[3]);
      }
    }

    // ---- prefetch next step's mask words (hides L2 latency behind softmax+PV) ----
    if (ks < 15){
      #pragma unroll
      for (int r = 0; r < 4; ++r) m16[r] = (unsigned int)pmrow[(size_t)r * SS + (size_t)(ks + 1) * 64];
    }

    // ---- in-lane softmax over heads, write W[ks&1] (XOR swizzle) ----
    unsigned short* Wc = &W[ks & 1][0];
    #pragma unroll
    for (int r = 0; r < 4; ++r){
      const int row = quad * 4 + r;
      float sv[HH];
      float m = -INFINITY;
      #pragma unroll
      for (int h = 0; h < HH; ++h){
        const unsigned int u = sp[h][r >> 1];
        const float f = (r & 1) ? bfhi(u) : bflo(u);
        sv[h] = f;
        m = fmaxf(m, f);
      }
      float sum = 0.f;
      #pragma unroll
      for (int h = 0; h < HH; ++h){
        const float e = (sv[h] != -INFINITY) ? __expf(sv[h] - m) : 0.f;
        sv[h] = e;
        sum += e;
      }
      const float rinv = (sum > 0.f) ? (1.0f / sum) : 0.f;
      const int col = (wave * 16 + l16) ^ ((row & 7) << 3);
      #pragma unroll
      for (int h = 0; h < HH; ++h){
        Wc[h * 1024 + row * 64 + col] = f2bf(sv[h] * rinv);
      }
    }
    __syncthreads();

    // ---- PV: this wave owns heads 4w..4w+3; Vt loads pipelined over heads ----
    {
      short8 aw[8];
      #pragma unroll
      for (int hh = 0; hh < 4; ++hh)
        #pragma unroll
        for (int kr = 0; kr < 2; ++kr){
          const int h = wave * 4 + hh;
          aw[hh * 2 + kr] = *(const short8*)&Wc[h * 1024 + l16 * 64 + ((kr * 32 + quad * 8) ^ ((l16 & 7) << 3))];
        }

      short8 vb[2][8];
      {
        const unsigned short* v0 = Vt + ((size_t)(b * HH + wave * 4) * DD + l16) * SS + k0 + quad * 8;
        #pragma unroll
        for (int kr = 0; kr < 2; ++kr)
          #pragma unroll
          for (int dt = 0; dt < 4; ++dt)
            vb[0][kr * 4 + dt] = *(const short8*)(v0 + (size_t)dt * 16 * SS + kr * 32);
      }
      #pragma unroll
      for (int hh = 0; hh < 4; ++hh){
        const int cur = hh & 1;
        if (hh < 3){
          const unsigned short* v1 = Vt + ((size_t)(b * HH + wave * 4 + hh + 1) * DD + l16) * SS + k0 + quad * 8;
          #pragma unroll
          for (int kr = 0; kr < 2; ++kr)
            #pragma unroll
            for (int dt = 0; dt < 4; ++dt)
              vb[cur ^ 1][kr * 4 + dt] = *(const short8*)(v1 + (size_t)dt * 16 * SS + kr * 32);
        }
        #pragma unroll
        for (int kr = 0; kr < 2; ++kr)
          #pragma unroll
          for (int dt = 0; dt < 4; ++dt)
            O[hh][dt] = __builtin_amdgcn_mfma_f32_16x16x32_bf16(aw[hh * 2 + kr], vb[cur][kr * 4 + dt], O[hh][dt], 0, 0, 0);
      }
    }
    // no second barrier: W is double-buffered; run-ahead bounded by barrier ks+1
  }

  // ---- epilogue: atomic accumulate split-k partials ----
  #pragma unroll
  for (int hh = 0; hh < 4; ++hh){
    const int h = wave * 4 + hh;
    #pragma unroll
    for (int dt = 0; dt < 4; ++dt){
      #pragma unroll
      for (int r = 0; r < 4; ++r){
        float* op = out + (((size_t)b * SS + (size_t)(q0 + quad * 4 + r)) * HH + h) * DD + dt * 16 + l16;
        unsafeAtomicAdd(op, O[hh][dt][r]);
      }
    }
  }
}

extern "C" void kernel_launch(void* const* d_in, const int* in_sizes, int n_in,
                              void* d_out, int out_size, void* d_ws, size_t ws_size,
                              hipStream_t stream)
{
  const float* Q = (const float*)d_in[0];
  const float* K = (const float*)d_in[1];
  const float* V = (const float*)d_in[2];
  const void* mask = d_in[3];

  uintptr_t base = (uintptr_t)d_ws;
  int* mode_ptr       = (int*)base;
  unsigned short* Qb  = (unsigned short*)(base + 64);
  unsigned short* Kb  = Qb + QE;
  unsigned short* Vt  = Kb + QE;
  unsigned short* pmp = Vt + QE;                 // 16.8 MB packed mask

  detect_mask_mode<<<1, 256, 0, stream>>>((const unsigned int*)mask, mode_ptr);
  pack_mask_kernel<<<(int)(PME / (256 * 8)), 256, 0, stream>>>(mask, mode_ptr, pmp);
  conv_bf16_kernel<<<2048, 256, 0, stream>>>(Q, Qb, 0.125f);
  conv_bf16_kernel<<<2048, 256, 0, stream>>>(K, Kb, 1.0f);
  transp_v_kernel<<<BB * HH * (SS / 64), 256, 0, stream>>>(V, Vt);
  hipMemsetAsync(d_out, 0, (size_t)out_size * sizeof(float), stream);

  attn_main_kernel<<<512, 256, 0, stream>>>(Qb, Kb, Vt, pmp, (float*)d_out);
}